// Round 1
// 204.865 us; speedup vs baseline: 1.0334x; 1.0334x over previous
//
#include <hip/hip_runtime.h>

// YOLOv1 loss: batch x 7 x 7 x 30 fp32 inputs (y_trues, y_preds) -> scalar.
// ~193 MB total input. Previous version was AoS (thread = cell, 120B rows):
// per-instruction lane stride of 120B made every wave load touch ~60 cache
// lines -> transaction-bound at 78us regardless of HBM vs L3 residency.
// This version stages each block's 256 cells into LDS via coalesced
// global_load_lds (16B/lane), then computes from LDS.

#define SS 49      // S*S
#define DD 30      // C + 5*B
#define BLOCK 256
#define CPB 256            // cells per block
#define TILE_F (CPB * DD)  // 7680 floats per array per tile (30720 B)

// Async, direct global->LDS copy, 16B per lane. Dest must be linear
// (wave-uniform base + lane*16) -- our staging loop is exactly that.
__device__ __forceinline__ void g2l16(const float* g, float* l) {
    __builtin_amdgcn_global_load_lds(
        (const __attribute__((address_space(1))) void*)g,
        (__attribute__((address_space(3))) void*)l,
        16, 0, 0);
}

__device__ __forceinline__ float iou_yolo(const float b1[4], const float b2[4]) {
    const float EPS = 1e-6f;
    float b1x1 = b1[0] - b1[2] * 0.5f, b1y1 = b1[1] - b1[3] * 0.5f;
    float b1x2 = b1[0] + b1[2] * 0.5f, b1y2 = b1[1] + b1[3] * 0.5f;
    float b2x1 = b2[0] - b2[2] * 0.5f, b2y1 = b2[1] - b2[3] * 0.5f;
    float b2x2 = b2[0] + b2[2] * 0.5f, b2y2 = b2[1] + b2[3] * 0.5f;
    float iw = fmaxf(fminf(b1x2, b2x2) - fmaxf(b1x1, b2x1), 0.0f);
    float ih = fmaxf(fminf(b1y2, b2y2) - fmaxf(b1y1, b2y1), 0.0f);
    float inter = iw * ih;
    float a1 = fabsf((b1x2 - b1x1) * (b1y2 - b1y1));
    float a2 = fabsf((b2x2 - b2x1) * (b2y2 - b2y1));
    return inter / (a1 + a2 - inter + EPS);
}

__global__ __launch_bounds__(BLOCK)
void yolo_loss_kernel(const float* __restrict__ yt_g,
                      const float* __restrict__ yp_g,
                      float* __restrict__ out,
                      int ncells, float inv_batch) {
    const float LAMBDA_COORD = 5.0f;
    const float LAMBDA_NOOBJ = 0.5f;
    const float EPS = 1e-6f;

    // 60 KB LDS -> 2 blocks/CU. Coalescing, not occupancy, is the lever here.
    __shared__ __align__(16) float lt[TILE_F];
    __shared__ __align__(16) float lp[TILE_F];

    const int tid = threadIdx.x;
    const int base_cell = blockIdx.x * CPB;
    const int nc = min(CPB, ncells - base_cell);
    const int nf = nc * DD;
    const int nf4 = nf >> 2;  // float4 count (1920 for a full tile)
    const size_t base_f = (size_t)base_cell * DD;

    const float* gt = yt_g + base_f;
    const float* gp = yp_g + base_f;

    // Coalesced staging: lane i of each wave copies 16B at a linear offset.
    for (int j = tid; j < nf4; j += BLOCK) {
        g2l16(gt + 4 * j, &lt[4 * j]);
        g2l16(gp + 4 * j, &lp[4 * j]);
    }
    // Scalar tail (only when nc*30 % 4 != 0; dormant for the bench shapes).
    for (int j = (nf4 << 2) + tid; j < nf; j += BLOCK) {
        lt[j] = gt[j];
        lp[j] = gp[j];
    }
    // __syncthreads() drains vmcnt (incl. global_load_lds) before the barrier.
    __syncthreads();

    float per_cell = 0.0f;
    if (tid < nc) {
        const float* yt = &lt[tid * DD];
        const float* yp = &lp[tid * DD];

        float obj = (yt[4] == 1.0f) ? 1.0f : 0.0f;
        float noobj = 1.0f - obj;

        float tb[4] = {yt[0], yt[1], yt[2], yt[3]};
        float pb1[4] = {yp[0], yp[1], yp[2], yp[3]};
        float pb2[4] = {yp[5], yp[6], yp[7], yp[8]};
        float iou1 = iou_yolo(tb, pb1);
        float iou2 = iou_yolo(tb, pb2);
        bool best1 = iou1 > iou2;

        float bh0 = best1 ? yp[0] : yp[5];
        float bh1 = best1 ? yp[1] : yp[6];
        float bh2 = best1 ? yp[2] : yp[7];
        float bh3 = best1 ? yp[3] : yp[8];
        float conf_hat       = best1 ? yp[4] : yp[9];
        float other_conf_hat = best1 ? yp[9] : yp[4];

        float dx = yt[0] - bh0, dy = yt[1] - bh1;
        float xy = dx * dx + dy * dy;

        float sw = sqrtf(yt[2]) - sqrtf(fabsf(bh2 + EPS));
        float sh = sqrtf(yt[3]) - sqrtf(fabsf(bh3 + EPS));
        float wh = sw * sw + sh * sh;

        float dc = yt[4] - conf_hat;
        float obj_conf = dc * dc;

        float noobj_in_obj = LAMBDA_NOOBJ * other_conf_hat * other_conf_hat;

        float d4 = yt[4] - yp[4];
        float d9 = yt[4] - yp[9];
        float noobj_cells = LAMBDA_NOOBJ * (d4 * d4 + d9 * d9);

        float cls = 0.0f;
#pragma unroll
        for (int k = 10; k < DD; ++k) {
            float d = yt[k] - yp[k];
            cls += d * d;
        }

        per_cell = obj * (LAMBDA_COORD * (xy + wh) + obj_conf + noobj_in_obj + cls)
                 + noobj * noobj_cells;
    }

    // Wave-level reduce (64 lanes), then cross-wave via LDS, one atomic/block.
#pragma unroll
    for (int off = 32; off > 0; off >>= 1)
        per_cell += __shfl_down(per_cell, off, 64);

    __shared__ float smem[BLOCK / 64];
    int lane = threadIdx.x & 63;
    int wave = threadIdx.x >> 6;
    if (lane == 0) smem[wave] = per_cell;
    __syncthreads();
    if (threadIdx.x == 0) {
        float s = smem[0] + smem[1] + smem[2] + smem[3];
        atomicAdd(out, s * inv_batch);
    }
}

extern "C" void kernel_launch(void* const* d_in, const int* in_sizes, int n_in,
                              void* d_out, int out_size, void* d_ws, size_t ws_size,
                              hipStream_t stream) {
    const float* yt = (const float*)d_in[0];
    const float* yp = (const float*)d_in[1];
    float* out = (float*)d_out;

    int total = in_sizes[0];          // batch * S*S * D
    int ncells = total / DD;          // batch * 49
    int batch = ncells / SS;

    // d_out is re-poisoned (0xAA) before every timed launch.
    hipMemsetAsync(out, 0, sizeof(float), stream);

    int grid = (ncells + CPB - 1) / CPB;
    yolo_loss_kernel<<<grid, BLOCK, 0, stream>>>(yt, yp, out, ncells,
                                                 1.0f / (float)batch);
}